// Round 4
// baseline (335.832 us; speedup 1.0000x reference)
//
#include <hip/hip_runtime.h>

// Segmented argmax (first-max tie-break) via packed u64 max.
// packed = (pred_bits << 32) | (0xFFFFFFFF - edge_idx); 0 = "no edge" sentinel.
//
// Round-2 evidence: FETCH 187 MB (inputs are only 102 MB) -> the per-XCD
// best-tables were being evicted from L2 by the streaming pred/dst reads,
// so filter loads missed L2 and dirty atomic lines churned to HBM (90 MB
// writes). Round-3 fix: non-temporal streaming loads keep the 800 KB live
// table resident in each XCD L2; filter loads become pipelined L2 hits.
// (Round-3 compile fix: __builtin_nontemporal_load needs clang ext_vector
// types, not HIP_vector_type structs.)

#define NXCD 8

typedef float fx4 __attribute__((ext_vector_type(4)));
typedef int   ix4 __attribute__((ext_vector_type(4)));

__device__ __forceinline__ unsigned get_xcc_id() {
    unsigned x;
    asm volatile("s_getreg_b32 %0, hwreg(HW_REG_XCC_ID)" : "=s"(x));
    return x & (NXCD - 1);
}

__device__ __forceinline__ unsigned long long pack(float p, unsigned i) {
    return ((unsigned long long)__float_as_uint(p) << 32) |
           (unsigned long long)(0xFFFFFFFFu - i);
}

template <bool LOCAL>
__global__ void edge_kernel(const float* __restrict__ pred,
                            const int* __restrict__ dst,
                            unsigned long long* __restrict__ best,
                            int e, int n) {
    unsigned long long* tbl =
        LOCAL ? best + (size_t)get_xcc_id() * n : best;

    const int nvec = e >> 2;
    int v = blockIdx.x * blockDim.x + threadIdx.x;
    if (v < nvec) {
        // Non-temporal: don't let the streaming inputs evict the table from L2.
        fx4 p4 = __builtin_nontemporal_load((const fx4*)pred + v);
        ix4 d4 = __builtin_nontemporal_load((const ix4*)dst + v);
        unsigned base = (unsigned)(v << 2);

        unsigned long long k0 = pack(p4.x, base + 0);
        unsigned long long k1 = pack(p4.y, base + 1);
        unsigned long long k2 = pack(p4.z, base + 2);
        unsigned long long k3 = pack(p4.w, base + 3);

        // Issue all 4 filter loads before any branch (MLP = 4).
        unsigned long long c0 = tbl[d4.x];
        unsigned long long c1 = tbl[d4.y];
        unsigned long long c2 = tbl[d4.z];
        unsigned long long c3 = tbl[d4.w];

        if (c0 < k0)
            (void)__hip_atomic_fetch_max(&tbl[d4.x], k0, __ATOMIC_RELAXED,
                LOCAL ? __HIP_MEMORY_SCOPE_WORKGROUP : __HIP_MEMORY_SCOPE_AGENT);
        if (c1 < k1)
            (void)__hip_atomic_fetch_max(&tbl[d4.y], k1, __ATOMIC_RELAXED,
                LOCAL ? __HIP_MEMORY_SCOPE_WORKGROUP : __HIP_MEMORY_SCOPE_AGENT);
        if (c2 < k2)
            (void)__hip_atomic_fetch_max(&tbl[d4.z], k2, __ATOMIC_RELAXED,
                LOCAL ? __HIP_MEMORY_SCOPE_WORKGROUP : __HIP_MEMORY_SCOPE_AGENT);
        if (c3 < k3)
            (void)__hip_atomic_fetch_max(&tbl[d4.w], k3, __ATOMIC_RELAXED,
                LOCAL ? __HIP_MEMORY_SCOPE_WORKGROUP : __HIP_MEMORY_SCOPE_AGENT);
    }

    // Tail (e % 4 edges) — negligible, let the first thread handle it.
    if (blockIdx.x == 0 && threadIdx.x == 0) {
        for (int i = (nvec << 2); i < e; ++i) {
            unsigned long long k = pack(pred[i], (unsigned)i);
            int d = dst[i];
            if (tbl[d] < k)
                (void)__hip_atomic_fetch_max(&tbl[d], k, __ATOMIC_RELAXED,
                    LOCAL ? __HIP_MEMORY_SCOPE_WORKGROUP : __HIP_MEMORY_SCOPE_AGENT);
        }
    }
}

__global__ void node_kernel(const unsigned long long* __restrict__ best,
                            const int* __restrict__ matched,
                            const int* __restrict__ src,
                            float* __restrict__ out_matched,
                            float* __restrict__ out_winpred,
                            float* __restrict__ found,
                            int n, int nrep) {
    int i = blockIdx.x * blockDim.x + threadIdx.x;
    if (i >= n) return;
    unsigned long long b = 0ULL;
    for (int r = 0; r < nrep; ++r) {
        unsigned long long v = best[(size_t)r * n + i];
        b = (v > b) ? v : b;
    }
    int m = matched[i];
    int nm = m;
    float wp = 0.0f;
    if (b != 0ULL) {
        wp = __uint_as_float((unsigned int)(b >> 32));
        unsigned int idx = 0xFFFFFFFFu - (unsigned int)(b & 0xFFFFFFFFu);
        if (m == -1 && wp > 0.5f) {
            nm = matched[src[idx]];
            *found = 1.0f;   // benign race: every writer stores 1.0f
        }
    }
    out_matched[i] = (float)nm;
    out_winpred[i] = wp;
}

extern "C" void kernel_launch(void* const* d_in, const int* in_sizes, int n_in,
                              void* d_out, int out_size, void* d_ws, size_t ws_size,
                              hipStream_t stream) {
    const float* edge_pred = (const float*)d_in[0];
    const int*   edge_index = (const int*)d_in[1];   // [2, E]: row0 = src, row1 = dst
    const int*   matched   = (const int*)d_in[2];

    const int e = in_sizes[0];
    const int n = in_sizes[2];

    const int* src = edge_index;
    const int* dst = edge_index + e;

    unsigned long long* best = (unsigned long long*)d_ws;

    float* out_matched = (float*)d_out;
    float* out_winpred = out_matched + n;
    float* found       = out_matched + 2 * n;

    const size_t need_local = (size_t)NXCD * n * sizeof(unsigned long long);
    const bool local = ws_size >= need_local;
    const int nrep = local ? NXCD : 1;

    (void)hipMemsetAsync(best, 0, (size_t)nrep * n * sizeof(unsigned long long), stream);
    (void)hipMemsetAsync(found, 0, sizeof(float), stream);

    const int block = 256;
    const int nvec = e >> 2;
    int grid_e = (nvec + block - 1) / block;
    if (grid_e < 1) grid_e = 1;
    if (local)
        edge_kernel<true><<<grid_e, block, 0, stream>>>(edge_pred, dst, best, e, n);
    else
        edge_kernel<false><<<grid_e, block, 0, stream>>>(edge_pred, dst, best, e, n);

    int grid_n = (n + block - 1) / block;
    node_kernel<<<grid_n, block, 0, stream>>>(best, matched, src,
                                              out_matched, out_winpred, found,
                                              n, nrep);
}

// Round 5
// 187.596 us; speedup vs baseline: 1.7902x; 1.7902x over previous
//
#include <hip/hip_runtime.h>

// Segmented argmax (first-max tie-break) via packed u64 max.
// packed = (pred_bits << 32) | (0xFFFFFFFF - edge_idx); 0 = "no edge" sentinel.
//
// Round-4 evidence: WRITE_SIZE == executed-atomic-count * 32B in every round
// -> global atomics are memory-side/write-through on gfx950 at ANY scope, and
// they leave the line uncacheable for the subsequent filter reads (84 MB of
// extra FETCH, ~900cyc misses). Round-5 fix: filter against a SHADOW table
// maintained with plain cached stores (L2-resident, races benign & monotone-
// ish); the atomicMax-only real table is never read in the hot loop.

#define NXCD 8

typedef float fx4 __attribute__((ext_vector_type(4)));
typedef int   ix4 __attribute__((ext_vector_type(4)));

__device__ __forceinline__ unsigned get_xcc_id() {
    unsigned x;
    asm volatile("s_getreg_b32 %0, hwreg(HW_REG_XCC_ID)" : "=s"(x));
    return x & (NXCD - 1);
}

__device__ __forceinline__ unsigned long long pack(float p, unsigned i) {
    return ((unsigned long long)__float_as_uint(p) << 32) |
           (unsigned long long)(0xFFFFFFFFu - i);
}

__device__ __forceinline__ unsigned long long shadow_ld(const unsigned long long* p) {
    return __hip_atomic_load(p, __ATOMIC_RELAXED, __HIP_MEMORY_SCOPE_WORKGROUP);
}
__device__ __forceinline__ void shadow_st(unsigned long long* p, unsigned long long v) {
    __hip_atomic_store(p, v, __ATOMIC_RELAXED, __HIP_MEMORY_SCOPE_WORKGROUP);
}

// APPROX: shadow-filtered, per-XCD replicas. LOCAL (no approx): per-XCD
// replicas, filter on real table. Neither: single table.
template <bool APPROX, bool LOCAL>
__global__ void edge_kernel(const float* __restrict__ pred,
                            const int* __restrict__ dst,
                            unsigned long long* __restrict__ best,
                            unsigned long long* __restrict__ apx_base,
                            int e, int n) {
    const unsigned xcc = (APPROX || LOCAL) ? get_xcc_id() : 0;
    unsigned long long* tbl = best + (size_t)xcc * n;
    unsigned long long* apx = APPROX ? apx_base + (size_t)xcc * n : tbl;

    const int nvec = e >> 2;
    int v = blockIdx.x * blockDim.x + threadIdx.x;
    if (v < nvec) {
        // Non-temporal: keep streams from evicting the shadow table from L2.
        fx4 p4 = __builtin_nontemporal_load((const fx4*)pred + v);
        ix4 d4 = __builtin_nontemporal_load((const ix4*)dst + v);
        unsigned base = (unsigned)(v << 2);

        unsigned long long k0 = pack(p4.x, base + 0);
        unsigned long long k1 = pack(p4.y, base + 1);
        unsigned long long k2 = pack(p4.z, base + 2);
        unsigned long long k3 = pack(p4.w, base + 3);

        // Issue all 4 filter loads before any branch (MLP = 4); these hit L2
        // because the shadow is written only with plain cached stores.
        unsigned long long c0 = shadow_ld(&apx[d4.x]);
        unsigned long long c1 = shadow_ld(&apx[d4.y]);
        unsigned long long c2 = shadow_ld(&apx[d4.z]);
        unsigned long long c3 = shadow_ld(&apx[d4.w]);

        if (c0 < k0) {
            (void)__hip_atomic_fetch_max(&tbl[d4.x], k0, __ATOMIC_RELAXED,
                                         __HIP_MEMORY_SCOPE_AGENT);
            if (APPROX) shadow_st(&apx[d4.x], k0);
        }
        if (c1 < k1) {
            (void)__hip_atomic_fetch_max(&tbl[d4.y], k1, __ATOMIC_RELAXED,
                                         __HIP_MEMORY_SCOPE_AGENT);
            if (APPROX) shadow_st(&apx[d4.y], k1);
        }
        if (c2 < k2) {
            (void)__hip_atomic_fetch_max(&tbl[d4.z], k2, __ATOMIC_RELAXED,
                                         __HIP_MEMORY_SCOPE_AGENT);
            if (APPROX) shadow_st(&apx[d4.z], k2);
        }
        if (c3 < k3) {
            (void)__hip_atomic_fetch_max(&tbl[d4.w], k3, __ATOMIC_RELAXED,
                                         __HIP_MEMORY_SCOPE_AGENT);
            if (APPROX) shadow_st(&apx[d4.w], k3);
        }
    }

    // Tail (e % 4 edges) — negligible.
    if (blockIdx.x == 0 && threadIdx.x == 0) {
        for (int i = (nvec << 2); i < e; ++i) {
            unsigned long long k = pack(pred[i], (unsigned)i);
            int d = dst[i];
            if (shadow_ld(&apx[d]) < k)
                (void)__hip_atomic_fetch_max(&tbl[d], k, __ATOMIC_RELAXED,
                                             __HIP_MEMORY_SCOPE_AGENT);
        }
    }
}

__global__ void node_kernel(const unsigned long long* __restrict__ best,
                            const int* __restrict__ matched,
                            const int* __restrict__ src,
                            float* __restrict__ out_matched,
                            float* __restrict__ out_winpred,
                            float* __restrict__ found,
                            int n, int nrep) {
    int i = blockIdx.x * blockDim.x + threadIdx.x;
    if (i >= n) return;
    unsigned long long b = 0ULL;
    for (int r = 0; r < nrep; ++r) {
        unsigned long long v = best[(size_t)r * n + i];
        b = (v > b) ? v : b;
    }
    int m = matched[i];
    int nm = m;
    float wp = 0.0f;
    if (b != 0ULL) {
        wp = __uint_as_float((unsigned int)(b >> 32));
        unsigned int idx = 0xFFFFFFFFu - (unsigned int)(b & 0xFFFFFFFFu);
        if (m == -1 && wp > 0.5f) {
            nm = matched[src[idx]];
            *found = 1.0f;   // benign race: every writer stores 1.0f
        }
    }
    out_matched[i] = (float)nm;
    out_winpred[i] = wp;
}

extern "C" void kernel_launch(void* const* d_in, const int* in_sizes, int n_in,
                              void* d_out, int out_size, void* d_ws, size_t ws_size,
                              hipStream_t stream) {
    const float* edge_pred = (const float*)d_in[0];
    const int*   edge_index = (const int*)d_in[1];   // [2, E]: row0 = src, row1 = dst
    const int*   matched   = (const int*)d_in[2];

    const int e = in_sizes[0];
    const int n = in_sizes[2];

    const int* src = edge_index;
    const int* dst = edge_index + e;

    unsigned long long* best = (unsigned long long*)d_ws;

    float* out_matched = (float*)d_out;
    float* out_winpred = out_matched + n;
    float* found       = out_matched + 2 * n;

    const size_t tbl_bytes = (size_t)n * sizeof(unsigned long long);
    const bool approx = ws_size >= 2 * NXCD * tbl_bytes;
    const bool local  = !approx && ws_size >= NXCD * tbl_bytes;
    const int nrep = (approx || local) ? NXCD : 1;

    unsigned long long* apx = best + (size_t)nrep * n;

    (void)hipMemsetAsync(best, 0,
                         (size_t)nrep * tbl_bytes * (approx ? 2 : 1), stream);
    (void)hipMemsetAsync(found, 0, sizeof(float), stream);

    const int block = 256;
    const int nvec = e >> 2;
    int grid_e = (nvec + block - 1) / block;
    if (grid_e < 1) grid_e = 1;
    if (approx)
        edge_kernel<true, true><<<grid_e, block, 0, stream>>>(
            edge_pred, dst, best, apx, e, n);
    else if (local)
        edge_kernel<false, true><<<grid_e, block, 0, stream>>>(
            edge_pred, dst, best, apx, e, n);
    else
        edge_kernel<false, false><<<grid_e, block, 0, stream>>>(
            edge_pred, dst, best, apx, e, n);

    int grid_n = (n + block - 1) / block;
    node_kernel<<<grid_n, block, 0, stream>>>(best, matched, src,
                                              out_matched, out_winpred, found,
                                              n, nrep);
}

// Round 6
// 115.155 us; speedup vs baseline: 2.9164x; 1.6291x over previous
//
#include <hip/hip_runtime.h>
#include <string.h>

// Segmented argmax (first-max tie-break), exact, via:
//   real table: u64 packed (pred_bits<<32)|(~idx), agent-scope atomicMax only
//   shadow:     u32 pred_bits, plain cached L2 stores (racy, benign, monotone-ish)
// Invariant: an edge is skipped only if shadow >= its pred_bits, and every
// shadow value was written together with a real-table atomic of >= pack value
// -> the real table is exact at kernel end.
//
// Round-5 evidence: WRITE_SIZE == 3.27M atomics * 32B (write-through memory-
// side RMWs), filter loads pace the rest. Round-6: threshold two-pass (high
// preds first -> pass 2 sees hot shadows, atomics ~1.3M), u32 shadow, MLP=8.

typedef float fx4 __attribute__((ext_vector_type(4)));
typedef int   ix4 __attribute__((ext_vector_type(4)));

__device__ __forceinline__ unsigned long long pack64(unsigned pbits, unsigned i) {
    return ((unsigned long long)pbits << 32) |
           (unsigned long long)(0xFFFFFFFFu - i);
}

__device__ __forceinline__ unsigned shadow_ld(const unsigned* p) {
    return __hip_atomic_load(p, __ATOMIC_RELAXED, __HIP_MEMORY_SCOPE_WORKGROUP);
}
__device__ __forceinline__ void shadow_st(unsigned* p, unsigned v) {
    __hip_atomic_store(p, v, __ATOMIC_RELAXED, __HIP_MEMORY_SCOPE_WORKGROUP);
}

// HIGH pass: edges with pred_bits >= tbits. LOW pass: the rest + tail.
template <bool HIGH>
__global__ void edge_pass(const float* __restrict__ pred,
                          const int* __restrict__ dst,
                          unsigned long long* __restrict__ tbl,
                          unsigned* __restrict__ shd,
                          int e, unsigned tbits) {
    const int nvec = e >> 2;
    const int half = (nvec + 1) >> 1;
    int v = blockIdx.x * blockDim.x + threadIdx.x;
    if (v < half) {
        fx4 pa = __builtin_nontemporal_load((const fx4*)pred + v);
        ix4 da = __builtin_nontemporal_load((const ix4*)dst + v);
        const bool hasb = (v + half) < nvec;
        const int vb = hasb ? v + half : v;   // duplicate slot is idempotent
        fx4 pb = __builtin_nontemporal_load((const fx4*)pred + vb);
        ix4 db = __builtin_nontemporal_load((const ix4*)dst + vb);

        const unsigned ba = (unsigned)(v << 2), bb = (unsigned)(vb << 2);
        unsigned pbv[8] = {__float_as_uint(pa.x), __float_as_uint(pa.y),
                           __float_as_uint(pa.z), __float_as_uint(pa.w),
                           __float_as_uint(pb.x), __float_as_uint(pb.y),
                           __float_as_uint(pb.z), __float_as_uint(pb.w)};
        int dv[8] = {da.x, da.y, da.z, da.w, db.x, db.y, db.z, db.w};
        unsigned iv[8] = {ba, ba + 1, ba + 2, ba + 3, bb, bb + 1, bb + 2, bb + 3};

        bool sel[8];
        unsigned c[8];
        #pragma unroll
        for (int k = 0; k < 8; ++k) {
            sel[k] = HIGH ? (pbv[k] >= tbits) : (pbv[k] < tbits);
            int a = sel[k] ? dv[k] : 0;       // unselected lanes merge on shd[0]
            c[k] = shadow_ld(&shd[a]);        // all 8 loads in flight (MLP=8)
        }
        #pragma unroll
        for (int k = 0; k < 8; ++k) {
            if (sel[k] && pbv[k] >= c[k]) {
                (void)__hip_atomic_fetch_max(&tbl[dv[k]], pack64(pbv[k], iv[k]),
                                             __ATOMIC_RELAXED,
                                             __HIP_MEMORY_SCOPE_AGENT);
                shadow_st(&shd[dv[k]], pbv[k]);
            }
        }
    }

    // Tail (e % 4 edges): only in the LOW pass, one thread, full processing.
    if (!HIGH && blockIdx.x == 0 && threadIdx.x == 0) {
        for (int i = (nvec << 2); i < e; ++i) {
            unsigned pb_ = __float_as_uint(pred[i]);
            int d = dst[i];
            if (pb_ >= shadow_ld(&shd[d])) {
                (void)__hip_atomic_fetch_max(&tbl[d], pack64(pb_, (unsigned)i),
                                             __ATOMIC_RELAXED,
                                             __HIP_MEMORY_SCOPE_AGENT);
                shadow_st(&shd[d], pb_);
            }
        }
    }
}

__global__ void node_kernel(const unsigned long long* __restrict__ best,
                            const int* __restrict__ matched,
                            const int* __restrict__ src,
                            float* __restrict__ out_matched,
                            float* __restrict__ out_winpred,
                            float* __restrict__ found,
                            int n) {
    int i = blockIdx.x * blockDim.x + threadIdx.x;
    if (i >= n) return;
    unsigned long long b = best[i];
    int m = matched[i];
    int nm = m;
    float wp = 0.0f;
    if (b != 0ULL) {
        wp = __uint_as_float((unsigned int)(b >> 32));
        unsigned int idx = 0xFFFFFFFFu - (unsigned int)(b & 0xFFFFFFFFu);
        if (m == -1 && wp > 0.5f) {
            nm = matched[src[idx]];
            *found = 1.0f;   // benign race: every writer stores 1.0f
        }
    }
    out_matched[i] = (float)nm;
    out_winpred[i] = wp;
}

extern "C" void kernel_launch(void* const* d_in, const int* in_sizes, int n_in,
                              void* d_out, int out_size, void* d_ws, size_t ws_size,
                              hipStream_t stream) {
    const float* edge_pred = (const float*)d_in[0];
    const int*   edge_index = (const int*)d_in[1];   // [2, E]: row0 = src, row1 = dst
    const int*   matched   = (const int*)d_in[2];

    const int e = in_sizes[0];
    const int n = in_sizes[2];

    const int* src = edge_index;
    const int* dst = edge_index + e;

    // ws layout: [ u64 tbl[n] | u32 shd[n] ]
    unsigned long long* tbl = (unsigned long long*)d_ws;
    unsigned* shd = (unsigned*)(tbl + n);

    float* out_matched = (float*)d_out;
    float* out_winpred = out_matched + n;
    float* found       = out_matched + 2 * n;

    (void)hipMemsetAsync(tbl, 0, (size_t)n * 12, stream);  // tbl + shd
    (void)hipMemsetAsync(found, 0, sizeof(float), stream);

    float tf = 0.9f;
    unsigned tbits;
    memcpy(&tbits, &tf, sizeof(tbits));

    const int block = 256;
    const int nvec = e >> 2;
    const int half = (nvec + 1) >> 1;
    int grid_e = (half + block - 1) / block;
    if (grid_e < 1) grid_e = 1;

    edge_pass<true><<<grid_e, block, 0, stream>>>(edge_pred, dst, tbl, shd, e, tbits);
    edge_pass<false><<<grid_e, block, 0, stream>>>(edge_pred, dst, tbl, shd, e, tbits);

    int grid_n = (n + block - 1) / block;
    node_kernel<<<grid_n, block, 0, stream>>>(tbl, matched, src,
                                              out_matched, out_winpred, found, n);
}

// Round 7
// 114.851 us; speedup vs baseline: 2.9241x; 1.0026x over previous
//
#include <hip/hip_runtime.h>
#include <string.h>

// Segmented argmax (first-max tie-break), exact:
//   real table: u64 packed (pred_bits<<32)|(~idx), agent-scope atomicMax only
//   shadow:     u32 pred_bits, plain cached stores (racy, benign)
// Skip an edge only if shadow > pred_bits... strictly: skip iff pred < shadow;
// equality proceeds to the atomic, so min-index tie-break is preserved.
//
// Round-6 evidence: HIGH and LOW passes both 59us despite ~9x different
// random-load and ~100x different atomic counts -> the 102 MB stream scan
// paces at only 1.7 TB/s (latency-bound, nt loads defeat L3 reuse).
// Round-7: plain cached loads (L3-resident across pass 2 + replays),
// MLP=8 stream loads per thread (4 stride-T vec4 chunks), block=512.

typedef float fx4 __attribute__((ext_vector_type(4)));
typedef int   ix4 __attribute__((ext_vector_type(4)));

#define CH 4   // vec4 chunks per thread (16 edges)

__device__ __forceinline__ unsigned long long pack64(unsigned pbits, unsigned i) {
    return ((unsigned long long)pbits << 32) |
           (unsigned long long)(0xFFFFFFFFu - i);
}

__device__ __forceinline__ unsigned shadow_ld(const unsigned* p) {
    return __hip_atomic_load(p, __ATOMIC_RELAXED, __HIP_MEMORY_SCOPE_WORKGROUP);
}
__device__ __forceinline__ void shadow_st(unsigned* p, unsigned v) {
    __hip_atomic_store(p, v, __ATOMIC_RELAXED, __HIP_MEMORY_SCOPE_WORKGROUP);
}

template <bool HIGH>
__global__ void edge_pass(const float* __restrict__ pred,
                          const int* __restrict__ dst,
                          unsigned long long* __restrict__ tbl,
                          unsigned* __restrict__ shd,
                          int e, unsigned tbits) {
    const int nvec = e >> 2;
    const int T = gridDim.x * blockDim.x;
    const int t = blockIdx.x * blockDim.x + threadIdx.x;

    // Issue all 8 stream loads (coalesced per wave at each stride offset)
    // before any dependent work: MLP = 8 on the HBM/L3 stream.
    fx4 p[CH];
    ix4 d[CH];
    int vi[CH];
    bool ok[CH];
    #pragma unroll
    for (int c = 0; c < CH; ++c) {
        vi[c] = t + c * T;
        ok[c] = vi[c] < nvec;
        int a = ok[c] ? vi[c] : 0;
        p[c] = ((const fx4*)pred)[a];
        d[c] = ((const ix4*)dst)[a];
    }

    #pragma unroll
    for (int c = 0; c < CH; ++c) {
        unsigned pbv[4] = {__float_as_uint(p[c].x), __float_as_uint(p[c].y),
                           __float_as_uint(p[c].z), __float_as_uint(p[c].w)};
        int dv[4] = {d[c].x, d[c].y, d[c].z, d[c].w};
        unsigned base = (unsigned)(vi[c] << 2);

        bool sel[4];
        unsigned cc[4];
        #pragma unroll
        for (int k = 0; k < 4; ++k) {
            sel[k] = ok[c] && (HIGH ? (pbv[k] >= tbits) : (pbv[k] < tbits));
            int a = sel[k] ? dv[k] : 0;     // unselected merge on shd[0]
            cc[k] = shadow_ld(&shd[a]);     // 4 filter loads in flight
        }
        #pragma unroll
        for (int k = 0; k < 4; ++k) {
            if (sel[k] && pbv[k] >= cc[k]) {
                (void)__hip_atomic_fetch_max(&tbl[dv[k]],
                                             pack64(pbv[k], base + k),
                                             __ATOMIC_RELAXED,
                                             __HIP_MEMORY_SCOPE_AGENT);
                shadow_st(&shd[dv[k]], pbv[k]);
            }
        }
    }

    // Tail (e % 4 edges): only in the LOW pass, one thread.
    if (!HIGH && blockIdx.x == 0 && threadIdx.x == 0) {
        for (int i = (nvec << 2); i < e; ++i) {
            unsigned pb_ = __float_as_uint(pred[i]);
            int dd = dst[i];
            if (pb_ >= shadow_ld(&shd[dd])) {
                (void)__hip_atomic_fetch_max(&tbl[dd], pack64(pb_, (unsigned)i),
                                             __ATOMIC_RELAXED,
                                             __HIP_MEMORY_SCOPE_AGENT);
                shadow_st(&shd[dd], pb_);
            }
        }
    }
}

__global__ void node_kernel(const unsigned long long* __restrict__ best,
                            const int* __restrict__ matched,
                            const int* __restrict__ src,
                            float* __restrict__ out_matched,
                            float* __restrict__ out_winpred,
                            float* __restrict__ found,
                            int n) {
    int i = blockIdx.x * blockDim.x + threadIdx.x;
    if (i >= n) return;
    unsigned long long b = best[i];
    int m = matched[i];
    int nm = m;
    float wp = 0.0f;
    if (b != 0ULL) {
        wp = __uint_as_float((unsigned int)(b >> 32));
        unsigned int idx = 0xFFFFFFFFu - (unsigned int)(b & 0xFFFFFFFFu);
        if (m == -1 && wp > 0.5f) {
            nm = matched[src[idx]];
            *found = 1.0f;   // benign race: every writer stores 1.0f
        }
    }
    out_matched[i] = (float)nm;
    out_winpred[i] = wp;
}

extern "C" void kernel_launch(void* const* d_in, const int* in_sizes, int n_in,
                              void* d_out, int out_size, void* d_ws, size_t ws_size,
                              hipStream_t stream) {
    const float* edge_pred = (const float*)d_in[0];
    const int*   edge_index = (const int*)d_in[1];   // [2, E]: row0 = src, row1 = dst
    const int*   matched   = (const int*)d_in[2];

    const int e = in_sizes[0];
    const int n = in_sizes[2];

    const int* src = edge_index;
    const int* dst = edge_index + e;

    // ws layout: [ u64 tbl[n] | u32 shd[n] ]
    unsigned long long* tbl = (unsigned long long*)d_ws;
    unsigned* shd = (unsigned*)(tbl + n);

    float* out_matched = (float*)d_out;
    float* out_winpred = out_matched + n;
    float* found       = out_matched + 2 * n;

    (void)hipMemsetAsync(tbl, 0, (size_t)n * 12, stream);  // tbl + shd
    (void)hipMemsetAsync(found, 0, sizeof(float), stream);

    float tf = 0.9f;
    unsigned tbits;
    memcpy(&tbits, &tf, sizeof(tbits));

    const int block = 512;
    const int nvec = e >> 2;
    const int nthreads = (nvec + CH - 1) / CH;
    int grid_e = (nthreads + block - 1) / block;
    if (grid_e < 1) grid_e = 1;

    edge_pass<true><<<grid_e, block, 0, stream>>>(edge_pred, dst, tbl, shd, e, tbits);
    edge_pass<false><<<grid_e, block, 0, stream>>>(edge_pred, dst, tbl, shd, e, tbits);

    int grid_n = (n + 255) / 256;
    node_kernel<<<grid_n, 256, 0, stream>>>(tbl, matched, src,
                                            out_matched, out_winpred, found, n);
}

// Round 8
// 106.993 us; speedup vs baseline: 3.1388x; 1.0735x over previous
//
#include <hip/hip_runtime.h>
#include <string.h>

// Segmented argmax (first-max tie-break), exact:
//   tbl: u64 packed (pred_bits<<32)|(~idx), agent-scope atomicMax (memory-side)
//   shd: u32 pred_bits filter. Seeded by a u32-atomicMax pass over the top
//        ~2.6% of edges (globally coherent), then read-mostly in the main pass.
// Exactness invariant: an edge is skipped only if pred_bits < shd[d], and
// shd[d] only ever holds a real pred of node d (so shd <= true max). Equality
// proceeds to the packed u64 atomicMax -> min-index tie-break preserved.
//
// Round-7 evidence: all rounds fit "global atomics ~26K ops/us device-wide";
// per-XCD-stale shadow caused ~2M admissions (8 independent H-processes).
// Round-8: seed shadow with ~330K coherent u32 atomics so the main pass
// admits only ~150K edges.

typedef float fx4 __attribute__((ext_vector_type(4)));
typedef int   ix4 __attribute__((ext_vector_type(4)));

#define CH 4   // vec4 chunks per thread (16 edges)

__device__ __forceinline__ unsigned long long pack64(unsigned pbits, unsigned i) {
    return ((unsigned long long)pbits << 32) |
           (unsigned long long)(0xFFFFFFFFu - i);
}

__device__ __forceinline__ unsigned shadow_ld(const unsigned* p) {
    return __hip_atomic_load(p, __ATOMIC_RELAXED, __HIP_MEMORY_SCOPE_WORKGROUP);
}
__device__ __forceinline__ void shadow_st(unsigned* p, unsigned v) {
    __hip_atomic_store(p, v, __ATOMIC_RELAXED, __HIP_MEMORY_SCOPE_WORKGROUP);
}

// Pass 1: seed the shadow with the true max over edges with pred >= tseed.
__global__ void seed_pass(const float* __restrict__ pred,
                          const int* __restrict__ dst,
                          unsigned* __restrict__ shd,
                          int e, unsigned tseed) {
    const int nvec = e >> 2;
    const int T = gridDim.x * blockDim.x;
    const int t = blockIdx.x * blockDim.x + threadIdx.x;

    fx4 p[CH];
    ix4 d[CH];
    int vi[CH];
    bool ok[CH];
    #pragma unroll
    for (int c = 0; c < CH; ++c) {
        vi[c] = t + c * T;
        ok[c] = vi[c] < nvec;
        int a = ok[c] ? vi[c] : 0;
        p[c] = ((const fx4*)pred)[a];
        d[c] = ((const ix4*)dst)[a];
    }

    #pragma unroll
    for (int c = 0; c < CH; ++c) {
        unsigned pbv[4] = {__float_as_uint(p[c].x), __float_as_uint(p[c].y),
                           __float_as_uint(p[c].z), __float_as_uint(p[c].w)};
        int dv[4] = {d[c].x, d[c].y, d[c].z, d[c].w};
        #pragma unroll
        for (int k = 0; k < 4; ++k) {
            if (ok[c] && pbv[k] >= tseed)
                (void)__hip_atomic_fetch_max(&shd[dv[k]], pbv[k],
                                             __ATOMIC_RELAXED,
                                             __HIP_MEMORY_SCOPE_AGENT);
        }
    }
}

// Pass 2: full scan; admit (u64 atomicMax) only edges not strictly below shadow.
__global__ void main_pass(const float* __restrict__ pred,
                          const int* __restrict__ dst,
                          unsigned long long* __restrict__ tbl,
                          unsigned* __restrict__ shd,
                          int e) {
    const int nvec = e >> 2;
    const int T = gridDim.x * blockDim.x;
    const int t = blockIdx.x * blockDim.x + threadIdx.x;

    fx4 p[CH];
    ix4 d[CH];
    int vi[CH];
    bool ok[CH];
    #pragma unroll
    for (int c = 0; c < CH; ++c) {
        vi[c] = t + c * T;
        ok[c] = vi[c] < nvec;
        int a = ok[c] ? vi[c] : 0;
        p[c] = ((const fx4*)pred)[a];
        d[c] = ((const ix4*)dst)[a];
    }

    #pragma unroll
    for (int c = 0; c < CH; ++c) {
        unsigned pbv[4] = {__float_as_uint(p[c].x), __float_as_uint(p[c].y),
                           __float_as_uint(p[c].z), __float_as_uint(p[c].w)};
        int dv[4] = {d[c].x, d[c].y, d[c].z, d[c].w};
        unsigned base = (unsigned)(vi[c] << 2);

        unsigned cc[4];
        #pragma unroll
        for (int k = 0; k < 4; ++k) {
            int a = ok[c] ? dv[k] : 0;
            cc[k] = shadow_ld(&shd[a]);     // 4 filter loads in flight
        }
        #pragma unroll
        for (int k = 0; k < 4; ++k) {
            if (ok[c] && pbv[k] >= cc[k]) {
                (void)__hip_atomic_fetch_max(&tbl[dv[k]],
                                             pack64(pbv[k], base + k),
                                             __ATOMIC_RELAXED,
                                             __HIP_MEMORY_SCOPE_AGENT);
                shadow_st(&shd[dv[k]], pbv[k]);  // throttle unseeded nodes
            }
        }
    }

    // Tail (e % 4 edges): one thread, exact.
    if (blockIdx.x == 0 && threadIdx.x == 0) {
        for (int i = (nvec << 2); i < e; ++i) {
            unsigned pb_ = __float_as_uint(pred[i]);
            int dd = dst[i];
            if (pb_ >= shadow_ld(&shd[dd])) {
                (void)__hip_atomic_fetch_max(&tbl[dd], pack64(pb_, (unsigned)i),
                                             __ATOMIC_RELAXED,
                                             __HIP_MEMORY_SCOPE_AGENT);
                shadow_st(&shd[dd], pb_);
            }
        }
    }
}

__global__ void node_kernel(const unsigned long long* __restrict__ best,
                            const int* __restrict__ matched,
                            const int* __restrict__ src,
                            float* __restrict__ out_matched,
                            float* __restrict__ out_winpred,
                            float* __restrict__ found,
                            int n) {
    int i = blockIdx.x * blockDim.x + threadIdx.x;
    if (i >= n) return;
    unsigned long long b = best[i];
    int m = matched[i];
    int nm = m;
    float wp = 0.0f;
    if (b != 0ULL) {
        wp = __uint_as_float((unsigned int)(b >> 32));
        unsigned int idx = 0xFFFFFFFFu - (unsigned int)(b & 0xFFFFFFFFu);
        if (m == -1 && wp > 0.5f) {
            nm = matched[src[idx]];
            *found = 1.0f;   // benign race: every writer stores 1.0f
        }
    }
    out_matched[i] = (float)nm;
    out_winpred[i] = wp;
}

extern "C" void kernel_launch(void* const* d_in, const int* in_sizes, int n_in,
                              void* d_out, int out_size, void* d_ws, size_t ws_size,
                              hipStream_t stream) {
    const float* edge_pred = (const float*)d_in[0];
    const int*   edge_index = (const int*)d_in[1];   // [2, E]: row0 = src, row1 = dst
    const int*   matched   = (const int*)d_in[2];

    const int e = in_sizes[0];
    const int n = in_sizes[2];

    const int* src = edge_index;
    const int* dst = edge_index + e;

    // ws layout: [ u64 tbl[n] | u32 shd[n] ]
    unsigned long long* tbl = (unsigned long long*)d_ws;
    unsigned* shd = (unsigned*)(tbl + n);

    float* out_matched = (float*)d_out;
    float* out_winpred = out_matched + n;
    float* found       = out_matched + 2 * n;

    (void)hipMemsetAsync(tbl, 0, (size_t)n * 12, stream);  // tbl + shd
    (void)hipMemsetAsync(found, 0, sizeof(float), stream);

    float ts = 0.974f;
    unsigned tseed;
    memcpy(&tseed, &ts, sizeof(tseed));

    const int block = 512;
    const int nvec = e >> 2;
    const int nthreads = (nvec + CH - 1) / CH;
    int grid_e = (nthreads + block - 1) / block;
    if (grid_e < 1) grid_e = 1;

    seed_pass<<<grid_e, block, 0, stream>>>(edge_pred, dst, shd, e, tseed);
    main_pass<<<grid_e, block, 0, stream>>>(edge_pred, dst, tbl, shd, e);

    int grid_n = (n + 255) / 256;
    node_kernel<<<grid_n, 256, 0, stream>>>(tbl, matched, src,
                                            out_matched, out_winpred, found, n);
}

// Round 9
// 71.324 us; speedup vs baseline: 4.7085x; 1.5001x over previous
//
#include <hip/hip_runtime.h>
#include <string.h>

// Segmented argmax (first-max tie-break), exact:
//   tbl: u64 packed (pred_bits<<32)|(~idx), agent-scope atomicMax (memory-side)
//   shd: u32 pred_bits filter, seeded by a coherent u32-atomicMax pass over
//        edges >= tseed; then an LDS BITMAP (1 bit/node: "seeded") lets the
//        main pass skip pred<tseed edges to seeded nodes with NO global load.
// Exactness: skip only if (seeded && pred < tseed <= truemax) or
// (pred < shd <= truemax). Equality always reaches the u64 atomicMax, which
// resolves min-index ties.
//
// Round-8 model fit (all rounds): t ~ stream(16us/scan) + randloads/280K·us
// + atomics/26K·us. Main pass was 45us of random filter loads. Round-9:
// bitmap-in-LDS filter removes ~85% of them.

typedef float fx4 __attribute__((ext_vector_type(4)));
typedef int   ix4 __attribute__((ext_vector_type(4)));

#define CH 4   // vec4 chunks per thread (16 edges)

__device__ __forceinline__ unsigned long long pack64(unsigned pbits, unsigned i) {
    return ((unsigned long long)pbits << 32) |
           (unsigned long long)(0xFFFFFFFFu - i);
}

__device__ __forceinline__ unsigned shadow_ld(const unsigned* p) {
    return __hip_atomic_load(p, __ATOMIC_RELAXED, __HIP_MEMORY_SCOPE_WORKGROUP);
}
__device__ __forceinline__ void shadow_st(unsigned* p, unsigned v) {
    __hip_atomic_store(p, v, __ATOMIC_RELAXED, __HIP_MEMORY_SCOPE_WORKGROUP);
}

// Pass 1: coherent seed — atomicMax shadow with every edge pred >= tseed.
__global__ void seed_pass(const float* __restrict__ pred,
                          const int* __restrict__ dst,
                          unsigned* __restrict__ shd,
                          int e, unsigned tseed) {
    const int nvec = e >> 2;
    const int T = gridDim.x * blockDim.x;
    const int t = blockIdx.x * blockDim.x + threadIdx.x;

    fx4 p[CH];
    ix4 d[CH];
    int vi[CH];
    bool ok[CH];
    #pragma unroll
    for (int c = 0; c < CH; ++c) {
        vi[c] = t + c * T;
        ok[c] = vi[c] < nvec;
        int a = ok[c] ? vi[c] : 0;
        p[c] = ((const fx4*)pred)[a];
        d[c] = ((const ix4*)dst)[a];
    }
    #pragma unroll
    for (int c = 0; c < CH; ++c) {
        unsigned pbv[4] = {__float_as_uint(p[c].x), __float_as_uint(p[c].y),
                           __float_as_uint(p[c].z), __float_as_uint(p[c].w)};
        int dv[4] = {d[c].x, d[c].y, d[c].z, d[c].w};
        #pragma unroll
        for (int k = 0; k < 4; ++k) {
            if (ok[c] && pbv[k] >= tseed)
                (void)__hip_atomic_fetch_max(&shd[dv[k]], pbv[k],
                                             __ATOMIC_RELAXED,
                                             __HIP_MEMORY_SCOPE_AGENT);
        }
    }
}

// Pass 2: bitmap build — bit i set iff shd[i] >= tseed ("seeded", final >= t).
__global__ void bitmap_pass(const unsigned* __restrict__ shd,
                            unsigned long long* __restrict__ bmp,
                            int n, unsigned tseed) {
    int node = blockIdx.x * blockDim.x + threadIdx.x;
    bool set = (node < n) && (shd[node] >= tseed);
    unsigned long long mask = __ballot(set);
    if ((threadIdx.x & 63) == 0) {
        int w = node >> 6;
        if (w < ((n + 63) >> 6)) bmp[w] = mask;
    }
}

// Pass 3: full scan; LDS-bitmap fast-skip, shd filter for the residual.
template <bool BMP>
__global__ void main_pass(const float* __restrict__ pred,
                          const int* __restrict__ dst,
                          unsigned long long* __restrict__ tbl,
                          unsigned* __restrict__ shd,
                          const unsigned long long* __restrict__ bmp,
                          int e, int n, unsigned tbits) {
    extern __shared__ unsigned long long lbmp[];
    const int nwords = (n + 63) >> 6;
    if (BMP) {
        for (int w = threadIdx.x; w < nwords; w += blockDim.x)
            lbmp[w] = bmp[w];
        __syncthreads();
    }

    const int nvec = e >> 2;
    const int T = gridDim.x * blockDim.x;
    const int t = blockIdx.x * blockDim.x + threadIdx.x;

    fx4 p[CH];
    ix4 d[CH];
    int vi[CH];
    bool ok[CH];
    #pragma unroll
    for (int c = 0; c < CH; ++c) {
        vi[c] = t + c * T;
        ok[c] = vi[c] < nvec;
        int a = ok[c] ? vi[c] : 0;
        p[c] = ((const fx4*)pred)[a];
        d[c] = ((const ix4*)dst)[a];
    }

    #pragma unroll
    for (int c = 0; c < CH; ++c) {
        unsigned pbv[4] = {__float_as_uint(p[c].x), __float_as_uint(p[c].y),
                           __float_as_uint(p[c].z), __float_as_uint(p[c].w)};
        int dv[4] = {d[c].x, d[c].y, d[c].z, d[c].w};
        unsigned base = (unsigned)(vi[c] << 2);

        bool slow[4];
        unsigned cc[4] = {0, 0, 0, 0};   // 0 = "admit" (conservative)
        #pragma unroll
        for (int k = 0; k < 4; ++k) {
            bool seeded = false;
            if (BMP)
                seeded = (lbmp[dv[k] >> 6] >> (dv[k] & 63)) & 1ULL;
            slow[k] = ok[c] && !(seeded && pbv[k] < tbits);
        }
        #pragma unroll
        for (int k = 0; k < 4; ++k)
            if (slow[k]) cc[k] = shadow_ld(&shd[dv[k]]);   // MLP on residual
        #pragma unroll
        for (int k = 0; k < 4; ++k) {
            if (slow[k] && pbv[k] >= cc[k]) {
                (void)__hip_atomic_fetch_max(&tbl[dv[k]],
                                             pack64(pbv[k], base + k),
                                             __ATOMIC_RELAXED,
                                             __HIP_MEMORY_SCOPE_AGENT);
                shadow_st(&shd[dv[k]], pbv[k]);  // throttle unseeded cascades
            }
        }
    }

    // Tail (e % 4 edges): one thread, exact via shd filter only.
    if (blockIdx.x == 0 && threadIdx.x == 0) {
        for (int i = (nvec << 2); i < e; ++i) {
            unsigned pb_ = __float_as_uint(pred[i]);
            int dd = dst[i];
            if (pb_ >= shadow_ld(&shd[dd])) {
                (void)__hip_atomic_fetch_max(&tbl[dd], pack64(pb_, (unsigned)i),
                                             __ATOMIC_RELAXED,
                                             __HIP_MEMORY_SCOPE_AGENT);
                shadow_st(&shd[dd], pb_);
            }
        }
    }
}

__global__ void node_kernel(const unsigned long long* __restrict__ best,
                            const int* __restrict__ matched,
                            const int* __restrict__ src,
                            float* __restrict__ out_matched,
                            float* __restrict__ out_winpred,
                            float* __restrict__ found,
                            int n) {
    int i = blockIdx.x * blockDim.x + threadIdx.x;
    if (i >= n) return;
    unsigned long long b = best[i];
    int m = matched[i];
    int nm = m;
    float wp = 0.0f;
    if (b != 0ULL) {
        wp = __uint_as_float((unsigned int)(b >> 32));
        unsigned int idx = 0xFFFFFFFFu - (unsigned int)(b & 0xFFFFFFFFu);
        if (m == -1 && wp > 0.5f) {
            nm = matched[src[idx]];
            *found = 1.0f;   // benign race: every writer stores 1.0f
        }
    }
    out_matched[i] = (float)nm;
    out_winpred[i] = wp;
}

extern "C" void kernel_launch(void* const* d_in, const int* in_sizes, int n_in,
                              void* d_out, int out_size, void* d_ws, size_t ws_size,
                              hipStream_t stream) {
    const float* edge_pred = (const float*)d_in[0];
    const int*   edge_index = (const int*)d_in[1];   // [2, E]: row0 = src, row1 = dst
    const int*   matched   = (const int*)d_in[2];

    const int e = in_sizes[0];
    const int n = in_sizes[2];

    const int* src = edge_index;
    const int* dst = edge_index + e;

    // ws layout: [ u64 tbl[n] | u32 shd[n] | u64 bmp[ceil(n/64)] ]
    unsigned long long* tbl = (unsigned long long*)d_ws;
    unsigned* shd = (unsigned*)(tbl + n);
    unsigned long long* bmp = (unsigned long long*)(shd + n);
    const int nwords = (n + 63) >> 6;

    float* out_matched = (float*)d_out;
    float* out_winpred = out_matched + n;
    float* found       = out_matched + 2 * n;

    (void)hipMemsetAsync(tbl, 0, (size_t)n * 12, stream);  // tbl + shd
    (void)hipMemsetAsync(found, 0, sizeof(float), stream);

    float ts = 0.97f;
    unsigned tseed;
    memcpy(&tseed, &ts, sizeof(tseed));

    const int block = 512;
    const int nvec = e >> 2;
    const int nthreads = (nvec + CH - 1) / CH;
    int grid_e = (nthreads + block - 1) / block;
    if (grid_e < 1) grid_e = 1;

    seed_pass<<<grid_e, block, 0, stream>>>(edge_pred, dst, shd, e, tseed);

    const size_t lds_bytes = (size_t)nwords * sizeof(unsigned long long);
    const bool use_bmp = lds_bytes <= 48 * 1024 &&
                         ws_size >= (size_t)n * 12 + lds_bytes;
    if (use_bmp) {
        int grid_b = (n + block - 1) / block;
        bitmap_pass<<<grid_b, block, 0, stream>>>(shd, bmp, n, tseed);
        main_pass<true><<<grid_e, block, lds_bytes, stream>>>(
            edge_pred, dst, tbl, shd, bmp, e, n, tseed);
    } else {
        main_pass<false><<<grid_e, block, 0, stream>>>(
            edge_pred, dst, tbl, shd, bmp, e, n, tseed);
    }

    int grid_n = (n + 255) / 256;
    node_kernel<<<grid_n, 256, 0, stream>>>(tbl, matched, src,
                                            out_matched, out_winpred, found, n);
}

// Round 10
// 70.946 us; speedup vs baseline: 4.7336x; 1.0053x over previous
//
#include <hip/hip_runtime.h>
#include <string.h>

// Segmented argmax (first-max tie-break), exact, three passes:
//  1. seed: stream PRED only; edges >= t gather dst sparsely and atomicMax
//     the u64 pack directly into tbl (high edges fully processed here).
//  2. bitmap: bit i = (tbl[i]>>32) >= t  (exact "node has a high edge").
//  3. main: stream pred+dst; high edge -> skip (done); low edge to seeded
//     node -> skip via LDS bitmap (truemax >= t > pred, no global load);
//     low edge to unseeded node -> shd plain-store-throttled filter + atomic.
// Exactness: every >=t edge reaches the u64 atomicMax; skips require
// pred < t <= truemax or pred < shd <= truemax; equality always proceeds
// (min-index tie-break via ~idx in the low word).
//
// Model (fits rounds 1-9): t = stream(16-18us/102MB) + randloads/280K·us
// + atomics/26K·us. Round-10 targets: seed loses its dst stream; main loses
// its 12.8M shd loads and most atomics.

typedef float fx4 __attribute__((ext_vector_type(4)));
typedef int   ix4 __attribute__((ext_vector_type(4)));

#define CH 4   // vec4 chunks per thread (16 edges)

__device__ __forceinline__ unsigned long long pack64(unsigned pbits, unsigned i) {
    return ((unsigned long long)pbits << 32) |
           (unsigned long long)(0xFFFFFFFFu - i);
}

__device__ __forceinline__ unsigned shadow_ld(const unsigned* p) {
    return __hip_atomic_load(p, __ATOMIC_RELAXED, __HIP_MEMORY_SCOPE_WORKGROUP);
}
__device__ __forceinline__ void shadow_st(unsigned* p, unsigned v) {
    __hip_atomic_store(p, v, __ATOMIC_RELAXED, __HIP_MEMORY_SCOPE_WORKGROUP);
}

// Pass 1: pred-only stream; high edges gather dst and atomicMax into tbl.
__global__ void seed_pass(const float* __restrict__ pred,
                          const int* __restrict__ dst,
                          unsigned long long* __restrict__ tbl,
                          int e, unsigned tbits) {
    const int nvec = e >> 2;
    const int T = gridDim.x * blockDim.x;
    const int t = blockIdx.x * blockDim.x + threadIdx.x;

    fx4 p[CH];
    int vi[CH];
    bool ok[CH];
    #pragma unroll
    for (int c = 0; c < CH; ++c) {
        vi[c] = t + c * T;
        ok[c] = vi[c] < nvec;
        p[c] = ((const fx4*)pred)[ok[c] ? vi[c] : 0];
    }
    #pragma unroll
    for (int c = 0; c < CH; ++c) {
        unsigned pbv[4] = {__float_as_uint(p[c].x), __float_as_uint(p[c].y),
                           __float_as_uint(p[c].z), __float_as_uint(p[c].w)};
        unsigned base = (unsigned)(vi[c] << 2);
        #pragma unroll
        for (int k = 0; k < 4; ++k) {
            if (ok[c] && pbv[k] >= tbits) {
                int d = dst[base + k];              // sparse gather (~2%)
                (void)__hip_atomic_fetch_max(&tbl[d], pack64(pbv[k], base + k),
                                             __ATOMIC_RELAXED,
                                             __HIP_MEMORY_SCOPE_AGENT);
            }
        }
    }
}

// Pass 2: bitmap from tbl — bit i set iff node i saw a >=t edge in seed.
__global__ void bitmap_pass(const unsigned long long* __restrict__ tbl,
                            unsigned long long* __restrict__ bmp,
                            int n, unsigned tbits) {
    int node = blockIdx.x * blockDim.x + threadIdx.x;
    bool set = (node < n) && ((unsigned)(tbl[node] >> 32) >= tbits);
    unsigned long long mask = __ballot(set);
    if ((threadIdx.x & 63) == 0) {
        int w = node >> 6;
        if (w < ((n + 63) >> 6)) bmp[w] = mask;
    }
}

// Pass 3: low edges only; bitmap fast-skip, shd slow path for unseeded nodes.
__global__ void main_pass(const float* __restrict__ pred,
                          const int* __restrict__ dst,
                          unsigned long long* __restrict__ tbl,
                          unsigned* __restrict__ shd,
                          const unsigned long long* __restrict__ bmp,
                          int e, int n, unsigned tbits) {
    extern __shared__ unsigned long long lbmp[];
    const int nwords = (n + 63) >> 6;
    for (int w = threadIdx.x; w < nwords; w += blockDim.x)
        lbmp[w] = bmp[w];
    __syncthreads();

    const int nvec = e >> 2;
    const int T = gridDim.x * blockDim.x;
    const int t = blockIdx.x * blockDim.x + threadIdx.x;

    fx4 p[CH];
    ix4 d[CH];
    int vi[CH];
    bool ok[CH];
    #pragma unroll
    for (int c = 0; c < CH; ++c) {
        vi[c] = t + c * T;
        ok[c] = vi[c] < nvec;
        int a = ok[c] ? vi[c] : 0;
        p[c] = ((const fx4*)pred)[a];
        d[c] = ((const ix4*)dst)[a];
    }

    #pragma unroll
    for (int c = 0; c < CH; ++c) {
        unsigned pbv[4] = {__float_as_uint(p[c].x), __float_as_uint(p[c].y),
                           __float_as_uint(p[c].z), __float_as_uint(p[c].w)};
        int dv[4] = {d[c].x, d[c].y, d[c].z, d[c].w};
        unsigned base = (unsigned)(vi[c] << 2);

        bool slow[4];
        unsigned cc[4] = {0, 0, 0, 0};
        #pragma unroll
        for (int k = 0; k < 4; ++k) {
            bool low = ok[c] && (pbv[k] < tbits);       // high edges done in seed
            bool seeded = (lbmp[dv[k] >> 6] >> (dv[k] & 63)) & 1ULL;
            slow[k] = low && !seeded;
        }
        #pragma unroll
        for (int k = 0; k < 4; ++k)
            if (slow[k]) cc[k] = shadow_ld(&shd[dv[k]]);   // MLP on residual
        #pragma unroll
        for (int k = 0; k < 4; ++k) {
            if (slow[k] && pbv[k] >= cc[k]) {
                (void)__hip_atomic_fetch_max(&tbl[dv[k]],
                                             pack64(pbv[k], base + k),
                                             __ATOMIC_RELAXED,
                                             __HIP_MEMORY_SCOPE_AGENT);
                shadow_st(&shd[dv[k]], pbv[k]);  // throttle unseeded cascades
            }
        }
    }

    // Tail (e % 4 edges): one thread, exact (always slow path; spurious
    // admissions to seeded nodes are harmless — idempotent max).
    if (blockIdx.x == 0 && threadIdx.x == 0) {
        for (int i = (nvec << 2); i < e; ++i) {
            unsigned pb_ = __float_as_uint(pred[i]);
            int dd = dst[i];
            if (pb_ >= shadow_ld(&shd[dd])) {
                (void)__hip_atomic_fetch_max(&tbl[dd], pack64(pb_, (unsigned)i),
                                             __ATOMIC_RELAXED,
                                             __HIP_MEMORY_SCOPE_AGENT);
                shadow_st(&shd[dd], pb_);
            }
        }
    }
}

__global__ void node_kernel(const unsigned long long* __restrict__ best,
                            const int* __restrict__ matched,
                            const int* __restrict__ src,
                            float* __restrict__ out_matched,
                            float* __restrict__ out_winpred,
                            float* __restrict__ found,
                            int n) {
    int i = blockIdx.x * blockDim.x + threadIdx.x;
    if (i >= n) return;
    unsigned long long b = best[i];
    int m = matched[i];
    int nm = m;
    float wp = 0.0f;
    if (b != 0ULL) {
        wp = __uint_as_float((unsigned int)(b >> 32));
        unsigned int idx = 0xFFFFFFFFu - (unsigned int)(b & 0xFFFFFFFFu);
        if (m == -1 && wp > 0.5f) {
            nm = matched[src[idx]];
            *found = 1.0f;   // benign race: every writer stores 1.0f
        }
    }
    out_matched[i] = (float)nm;
    out_winpred[i] = wp;
}

extern "C" void kernel_launch(void* const* d_in, const int* in_sizes, int n_in,
                              void* d_out, int out_size, void* d_ws, size_t ws_size,
                              hipStream_t stream) {
    const float* edge_pred = (const float*)d_in[0];
    const int*   edge_index = (const int*)d_in[1];   // [2, E]: row0 = src, row1 = dst
    const int*   matched   = (const int*)d_in[2];

    const int e = in_sizes[0];
    const int n = in_sizes[2];

    const int* src = edge_index;
    const int* dst = edge_index + e;

    // ws layout: [ u64 tbl[n] | u32 shd[n] | u64 bmp[ceil(n/64)] ]
    unsigned long long* tbl = (unsigned long long*)d_ws;
    unsigned* shd = (unsigned*)(tbl + n);
    unsigned long long* bmp = (unsigned long long*)(shd + n);
    const int nwords = (n + 63) >> 6;

    float* out_matched = (float*)d_out;
    float* out_winpred = out_matched + n;
    float* found       = out_matched + 2 * n;

    (void)hipMemsetAsync(tbl, 0, (size_t)n * 12, stream);  // tbl + shd
    (void)hipMemsetAsync(found, 0, sizeof(float), stream);

    float ts = 0.98f;
    unsigned tbits;
    memcpy(&tbits, &ts, sizeof(tbits));

    const int block = 512;
    const int nvec = e >> 2;
    const int nthreads = (nvec + CH - 1) / CH;
    int grid_e = (nthreads + block - 1) / block;
    if (grid_e < 1) grid_e = 1;

    seed_pass<<<grid_e, block, 0, stream>>>(edge_pred, dst, tbl, e, tbits);

    int grid_b = (n + block - 1) / block;
    bitmap_pass<<<grid_b, block, 0, stream>>>(tbl, bmp, n, tbits);

    const size_t lds_bytes = (size_t)nwords * sizeof(unsigned long long);
    main_pass<<<grid_e, block, lds_bytes, stream>>>(
        edge_pred, dst, tbl, shd, bmp, e, n, tbits);

    int grid_n = (n + 255) / 256;
    node_kernel<<<grid_n, 256, 0, stream>>>(tbl, matched, src,
                                            out_matched, out_winpred, found, n);
}